// Round 7
// baseline (3420.897 us; speedup 1.0000x reference)
//
#include <hip/hip_runtime.h>
#include <hip/hip_bf16.h>

#define TS 256
#define BB 128
#define II 1024
#define HH 1024
#define PP 512
#define GG 4096  // 4*H
#define NWG 128       // 2 groups x 64 WGs
#define NGRP 2
#define WPG 64        // WGs per group (hidden tiles)
#define BT 64         // batch rows per group
#define HCW 16        // hidden cols per WG
#define BSTRIDE 1032  // shorts per Bs row (pad 1024+8 to spread banks)
#define NFLAGS (NGRP * 4 * WPG)  // [grp][wave][jj]
#define SMEM_BYTES (64 * BSTRIDE * 2)  // 132096

typedef __attribute__((ext_vector_type(8))) short bf16x8;
typedef __attribute__((ext_vector_type(4))) float f32x4;

__device__ __forceinline__ short f2bs(float f) {
    __hip_bfloat16 h = __float2bfloat16(f);
    return __builtin_bit_cast(short, h);
}
__device__ __forceinline__ float bs2f(short s) {
    return __bfloat162float(__builtin_bit_cast(__hip_bfloat16, s));
}

__device__ __forceinline__ bf16x8 ld8(const __hip_bfloat16* p) {
    return *(const bf16x8*)p;
}
__device__ __forceinline__ bf16x8 ld8(const float* p) {
    f32x4 lo = *(const f32x4*)p;
    f32x4 hi = *(const f32x4*)(p + 4);
    bf16x8 r;
#pragma unroll
    for (int i = 0; i < 4; ++i) { r[i] = f2bs(lo[i]); r[4 + i] = f2bs(hi[i]); }
    return r;
}

__device__ __forceinline__ void stv(float* p, long i, float v) { p[i] = v; }
__device__ __forceinline__ void stv(__hip_bfloat16* p, long i, float v) { p[i] = __float2bfloat16(v); }

// Coherent write-through bf16 store (sc0 sc1): visible at the device coherence point.
__device__ __forceinline__ void st_bf16_wt(__hip_bfloat16* p, float v) {
    int si = (int)f2bs(v);
    asm volatile("global_store_short %0, %1, off sc0 sc1" :: "v"(p), "v"(si));
}
// Coherent 16B load (bypass stale L1/L2): reads the coherence point.
__device__ __forceinline__ f32x4 ld16_mall(const void* p) {
    f32x4 r;
    asm volatile("global_load_dwordx4 %0, %1, off sc0 sc1" : "=&v"(r) : "v"(p));
    return r;
}
__device__ __forceinline__ void vm_drain() {
    asm volatile("s_waitcnt vmcnt(0)" ::: "memory");
}

// C[M,N] = A[M,K] @ B[N,K]^T, MFMA bf16. 128x128 tile, BK=32, 4 waves (64x64 each).
template <typename AT, typename BT_, typename CT>
__global__ __launch_bounds__(256) void mfma_gemm_bt(const AT* __restrict__ A,
                                                    const BT_* __restrict__ B,
                                                    CT* __restrict__ C,
                                                    int M, int N, int K) {
    __shared__ __align__(16) short As[128][40];
    __shared__ __align__(16) short Bsh[128][40];
    const int tid = threadIdx.x;
    const long bm = (long)blockIdx.y * 128;
    const long bn = (long)blockIdx.x * 128;
    const int lane = tid & 63, wv = tid >> 6;
    const int l15 = lane & 15, quad = lane >> 4;
    const int wm = (wv >> 1) * 64, wn = (wv & 1) * 64;
    f32x4 acc[4][4] = {};
    for (int k0 = 0; k0 < K; k0 += 32) {
#pragma unroll
        for (int i = 0; i < 2; ++i) {
            int ch = tid + 256 * i;
            int row = ch >> 2, koff = (ch & 3) * 8;
            *(bf16x8*)&As[row][koff] = ld8(&A[(bm + row) * (long)K + k0 + koff]);
            *(bf16x8*)&Bsh[row][koff] = ld8(&B[(bn + row) * (long)K + k0 + koff]);
        }
        __syncthreads();
        bf16x8 af[4], bfv[4];
#pragma unroll
        for (int t = 0; t < 4; ++t) {
            af[t] = *(const bf16x8*)&As[wm + t * 16 + l15][quad * 8];
            bfv[t] = *(const bf16x8*)&Bsh[wn + t * 16 + l15][quad * 8];
        }
#pragma unroll
        for (int mt = 0; mt < 4; ++mt)
#pragma unroll
            for (int nt = 0; nt < 4; ++nt)
                acc[mt][nt] = __builtin_amdgcn_mfma_f32_16x16x32_bf16(af[mt], bfv[nt], acc[mt][nt], 0, 0, 0);
        __syncthreads();
    }
#pragma unroll
    for (int mt = 0; mt < 4; ++mt)
#pragma unroll
        for (int nt = 0; nt < 4; ++nt)
#pragma unroll
            for (int r = 0; r < 4; ++r) {
                long row = bm + wm + mt * 16 + quad * 4 + r;
                long col = bn + wn + nt * 16 + l15;
                stv(C, row * N + col, acc[mt][nt][r]);
            }
}

// 4 gate-MFMAs for one K-chunk. Bs rows ordered [gate g 0..3][hcol h 0..15].
__device__ __forceinline__ void mfma4(bf16x8 av, const short* bp, f32x4* acc) {
    acc[0] = __builtin_amdgcn_mfma_f32_16x16x32_bf16(av, *(const bf16x8*)(bp), acc[0], 0, 0, 0);
    acc[1] = __builtin_amdgcn_mfma_f32_16x16x32_bf16(av, *(const bf16x8*)(bp + 16 * BSTRIDE), acc[1], 0, 0, 0);
    acc[2] = __builtin_amdgcn_mfma_f32_16x16x32_bf16(av, *(const bf16x8*)(bp + 32 * BSTRIDE), acc[2], 0, 0, 0);
    acc[3] = __builtin_amdgcn_mfma_f32_16x16x32_bf16(av, *(const bf16x8*)(bp + 48 * BSTRIDE), acc[3], 0, 0, 0);
}

// Cooperative recurrence: 2 batch-groups x 64 WGs; WG = (grp, jj): batch rows
// [64*grp, +64), hidden cols [16*jj, +16). Each WAVE owns a complete slice:
// 16 batch rows x 16 hidden cols x full K — no reduce, no __syncthreads in the
// main loop. A-loads are processed in TWO bounded phases of 16 asm loads each
// (<=16 live asm-output vectors: prevents the allocator spilling a not-yet-
// written asm load destination, the round-5/6 corruption). Protocol (round-4
// proven): sc0sc1 h stores -> vmcnt(0) drain -> relaxed agent flag store;
// consumer spins on its 64 producer flags (1/lane) then issues sc0sc1 A loads.
__global__ __launch_bounds__(256) void lstm_rec_k(
    const __hip_bfloat16* __restrict__ h0b,   // [128][512]
    const float* __restrict__ c0,             // [128][1024]
    const float* __restrict__ Whh,            // [4096][512] fp32
    const __hip_bfloat16* __restrict__ Wcomb, // [4096][1024]
    const __hip_bfloat16* __restrict__ xg,    // [256][128][4096]
    __hip_bfloat16* __restrict__ hfull,       // [256][128][1024]
    float* __restrict__ cT,                   // [128][1024]
    unsigned* __restrict__ flags) {           // [2][4][64]
    extern __shared__ char smem[];
    short* Bs = (short*)smem;                 // [64][BSTRIDE] bf16

    const int tid = threadIdx.x;
    const int wg = blockIdx.x;
    const int grp = wg >> 6;                  // 0..1
    const int jj = wg & 63;
    const int hc0 = jj * HCW;
    const int bt = grp * BT;
    const int lane = tid & 63, wv = tid >> 6;
    const int l15 = lane & 15, quad = lane >> 4;
    unsigned* fbase = flags + grp * (4 * WPG) + wv * WPG;  // this wave's flag row
    const int brow = bt + wv * 16 + quad * 4;  // C rows (+r)
    const int arow = bt + wv * 16 + l15;       // A-fragment row
    const short* bp0 = Bs + l15 * BSTRIDE + quad * 8;

    // Stage B(t=0): 64 rows (g*16+h) = Whh[g*1024 + hc0 + h][0..512), fp32 -> bf16
    for (int ch = tid; ch < 64 * 64; ch += 256) {
        int row = ch >> 6, koff = (ch & 63) * 8;
        long wr = (long)(row >> 4) * HH + hc0 + (row & 15);
        *(bf16x8*)&Bs[row * BSTRIDE + koff] = ld8(&Whh[wr * PP + koff]);
    }

    float creg[4];
#pragma unroll
    for (int r = 0; r < 4; ++r) creg[r] = c0[(long)(brow + r) * HH + hc0 + l15];

    short xr[16];
    auto ldxg = [&](int t) {  // plain loads: xg is read-only precomputed (no coherence
                              // concern); compiler hazard-tracks + spills these safely
        const __hip_bfloat16* xgt = xg + (long)t * BB * GG;
#pragma unroll
        for (int g = 0; g < 4; ++g)
#pragma unroll
            for (int r = 0; r < 4; ++r)
                xr[g * 4 + r] = *(const short*)(xgt + (long)(brow + r) * GG + g * HH + hc0 + l15);
    };

    // Per-wave spin: 64 producer flags, one per lane (relaxed agent loads).
    auto wave_wait = [&](int want) {
        for (;;) {
            unsigned v = __hip_atomic_load(&fbase[lane], __ATOMIC_RELAXED,
                                           __HIP_MEMORY_SCOPE_AGENT);
            if (__all((int)(v >= (unsigned)want))) break;
            __builtin_amdgcn_s_sleep(1);
        }
    };

    // In-register cell + coherent stores + drain + own flag.
    auto finish = [&](f32x4* acc, int t, bool flag) {
        __hip_bfloat16* hp = hfull + (long)t * BB * HH + (long)brow * HH + hc0 + l15;
#pragma unroll
        for (int r = 0; r < 4; ++r) {
            float gi = acc[0][r] + bs2f(xr[r]);
            float gf = acc[1][r] + bs2f(xr[4 + r]);
            float gg = acc[2][r] + bs2f(xr[8 + r]);
            float go = acc[3][r] + bs2f(xr[12 + r]);
            float i_ = 1.f / (1.f + expf(-gi));
            float f_ = 1.f / (1.f + expf(-gf));
            float g_ = tanhf(gg);
            float o_ = 1.f / (1.f + expf(-go));
            float c = f_ * creg[r] + i_ * g_;
            creg[r] = c;
            st_bf16_wt(hp + (long)r * HH, o_ * tanhf(c));
        }
        vm_drain();  // this wave's 16 rows acked at the coherence point
        if (flag && lane == 0) {
            __hip_atomic_store(&fbase[jj], (unsigned)(t + 1),
                               __ATOMIC_RELAXED, __HIP_MEMORY_SCOPE_AGENT);
        }
    };

    // Bounded-window A phase: 16 asm loads -> vmcnt(0) -> sched_barrier -> 16 MFMA quads.
    auto a_phase = [&](const __hip_bfloat16* ap, int c0_, f32x4* acc) {
        f32x4 avr[16];
#pragma unroll
        for (int i = 0; i < 16; ++i) avr[i] = ld16_mall(ap + (c0_ + i) * 32);
        asm volatile("s_waitcnt vmcnt(0)" ::: "memory");
        __builtin_amdgcn_sched_barrier(0);
#pragma unroll
        for (int i = 0; i < 16; ++i)
            mfma4(__builtin_bit_cast(bf16x8, avr[i]), bp0 + (c0_ + i) * 32, acc);
        __builtin_amdgcn_sched_barrier(0);  // keep next phase's loads out of this window
    };

    // ---- t = 0: A = h0b (K=512), B = Whh ----
    ldxg(0);
    __syncthreads();  // Bs staged
    {
        f32x4 acc[4] = {};
        a_phase(h0b + (long)arow * PP + quad * 8, 0, acc);
        finish(acc, 0, true);
    }
    __syncthreads();  // all waves done reading Bs(Whh)
    // Restage B for t>=1: Wcomb rows (bf16, K=1024)
    for (int ch = tid; ch < 64 * 128; ch += 256) {
        int row = ch >> 7, koff = (ch & 127) * 8;
        long wr = (long)(row >> 4) * HH + hc0 + (row & 15);
        *(bf16x8*)&Bs[row * BSTRIDE + koff] = *(const bf16x8*)&Wcomb[wr * HH + koff];
    }
    __syncthreads();

    // ---- main loop: zero block-level synchronization ----
    for (int t = 1; t < TS; ++t) {
        ldxg(t);        // plain loads; overlap with the spin
        wave_wait(t);   // this wave's 64 producers have published h(t-1)
        const __hip_bfloat16* ap = hfull + ((long)(t - 1) * BB + arow) * HH + quad * 8;
        f32x4 acc[4] = {};
        a_phase(ap, 0, acc);
        a_phase(ap, 16, acc);
        finish(acc, t, t < TS - 1);
    }

#pragma unroll
    for (int r = 0; r < 4; ++r) cT[(long)(brow + r) * HH + hc0 + l15] = creg[r];
}

// h0 cast to bf16; Whr transpose (fp32); zero the barrier flags.
__global__ __launch_bounds__(256) void prep_k(const float* __restrict__ h0,
                                              __hip_bfloat16* __restrict__ h0b,
                                              const float* __restrict__ Whr,
                                              float* __restrict__ WhrT,
                                              unsigned* __restrict__ flags) {
    int i = blockIdx.x * 256 + threadIdx.x;
    if (i < NFLAGS) flags[i] = 0u;
    if (i < BB * PP) h0b[i] = __float2bfloat16(h0[i]);
    if (i < PP * HH) {
        int h = i / PP, p = i % PP;
        WhrT[i] = Whr[(long)p * HH + h];
    }
}

__global__ __launch_bounds__(256) void tail_k(const float* __restrict__ ys_last,
                                              float* __restrict__ hT) {
    int i = blockIdx.x * 256 + threadIdx.x;
    hT[i] = ys_last[i];
}

extern "C" void kernel_launch(void* const* d_in, const int* in_sizes, int n_in,
                              void* d_out, int out_size, void* d_ws, size_t ws_size,
                              hipStream_t stream) {
    const float* x   = (const float*)d_in[0];  // [T,B,I]
    const float* h0  = (const float*)d_in[1];  // [1,B,P]
    const float* c0  = (const float*)d_in[2];  // [1,B,H]
    const float* Wih = (const float*)d_in[3];  // [4H,I]
    const float* Whh = (const float*)d_in[4];  // [4H,P]
    const float* Whr = (const float*)d_in[5];  // [P,H]

    float* out = (float*)d_out;
    float* ys = out;                           // [T,B,P]
    float* hT = out + (long)TS * BB * PP;      // [B,P]
    float* cT = hT + (long)BB * PP;            // [B,H]

    char* ws = (char*)d_ws;
    size_t off = 0;
    __hip_bfloat16* xg = (__hip_bfloat16*)(ws + off);    off += (size_t)TS * BB * GG * 2;
    __hip_bfloat16* hfull = (__hip_bfloat16*)(ws + off); off += (size_t)TS * BB * HH * 2;
    __hip_bfloat16* Wcomb = (__hip_bfloat16*)(ws + off); off += (size_t)GG * HH * 2;
    float* WhrT = (float*)(ws + off);                    off += (size_t)HH * PP * 4;
    __hip_bfloat16* h0b = (__hip_bfloat16*)(ws + off);   off += (size_t)BB * PP * 2;
    unsigned* flags = (unsigned*)(ws + off);             off += 4096;

    static int smem_inited = 0;
    if (!smem_inited) {
        (void)hipFuncSetAttribute(reinterpret_cast<const void*>(lstm_rec_k),
                                  hipFuncAttributeMaxDynamicSharedMemorySize, SMEM_BYTES);
        smem_inited = 1;
    }

    dim3 blk(256);

    // prep: h0 -> bf16, Whr -> WhrT, zero flags
    prep_k<<<dim3((PP * HH) / 256), blk, 0, stream>>>(h0, h0b, Whr, WhrT, flags);

    // xg[T*B, 4H] = x @ W_ih^T
    mfma_gemm_bt<float, float, __hip_bfloat16>
        <<<dim3(GG / 128, (TS * BB) / 128), blk, 0, stream>>>(x, Wih, xg, TS * BB, GG, II);

    // W_comb[4H, H] = W_hh @ W_hr
    mfma_gemm_bt<float, float, __hip_bfloat16>
        <<<dim3(HH / 128, GG / 128), blk, 0, stream>>>(Whh, WhrT, Wcomb, GG, HH, PP);

    // full recurrence (cooperative launch for co-residency; per-wave flag protocol)
    {
        const __hip_bfloat16* a0 = h0b;
        const float* a1 = c0;
        const float* a2 = Whh;
        const __hip_bfloat16* a3 = Wcomb;
        const __hip_bfloat16* a4 = xg;
        __hip_bfloat16* a5 = hfull;
        float* a6 = cT;
        unsigned* a7 = flags;
        void* args[] = {(void*)&a0, (void*)&a1, (void*)&a2, (void*)&a3,
                        (void*)&a4, (void*)&a5, (void*)&a6, (void*)&a7};
        (void)hipLaunchCooperativeKernel(reinterpret_cast<void*>(lstm_rec_k),
                                         dim3(NWG), blk, args, SMEM_BYTES, stream);
    }

    // ys[T*B, P] = hfull @ W_hr^T
    mfma_gemm_bt<__hip_bfloat16, float, float>
        <<<dim3(PP / 128, (TS * BB) / 128), blk, 0, stream>>>(hfull, Whr, ys, TS * BB, PP, HH);

    // hT = ys[T-1]
    tail_k<<<dim3((BB * PP) / 256), blk, 0, stream>>>(ys + (long)(TS - 1) * BB * PP, hT);
}

// Round 8
// 3356.898 us; speedup vs baseline: 1.0191x; 1.0191x over previous
//
#include <hip/hip_runtime.h>
#include <hip/hip_bf16.h>

#define TS 256
#define BB 128
#define II 1024
#define HH 1024
#define PP 512
#define GG 4096  // 4*H
#define NWG 256
#define NGRP 4
#define WPG 64        // WGs per group (hidden tiles)
#define BT 32         // batch rows per group
#define HCW 16        // hidden cols per WG
#define BSTRIDE 1032  // shorts per Bs row (pad 1024+8 to spread banks)
#define RSTRIDE 20    // floats per red row (pad 16+4)
#define HSTRIDE (BB * HH + 1024)  // hfull per-step stride (elems): 2KB guard vs prefetch
#define NFLAGS (NGRP * 2 * WPG)
#define SMEM_BYTES (64 * BSTRIDE * 2 + 2 * 64 * RSTRIDE * 4)  // 142336

typedef __attribute__((ext_vector_type(8))) short bf16x8;
typedef __attribute__((ext_vector_type(4))) float f32x4;

__device__ __forceinline__ short f2bs(float f) {
    __hip_bfloat16 h = __float2bfloat16(f);
    return __builtin_bit_cast(short, h);
}
__device__ __forceinline__ float bs2f(short s) {
    return __bfloat162float(__builtin_bit_cast(__hip_bfloat16, s));
}

__device__ __forceinline__ bf16x8 ld8(const __hip_bfloat16* p) {
    return *(const bf16x8*)p;
}
__device__ __forceinline__ bf16x8 ld8(const float* p) {
    f32x4 lo = *(const f32x4*)p;
    f32x4 hi = *(const f32x4*)(p + 4);
    bf16x8 r;
#pragma unroll
    for (int i = 0; i < 4; ++i) { r[i] = f2bs(lo[i]); r[4 + i] = f2bs(hi[i]); }
    return r;
}

__device__ __forceinline__ void stv(float* p, long i, float v) { p[i] = v; }
__device__ __forceinline__ void stv(__hip_bfloat16* p, long i, float v) { p[i] = __float2bfloat16(v); }

// Coherent write-through bf16 store (sc0 sc1): lands at the device coherence point;
// produced h is never dirty in the producer's L2 -> consumer L2 misses get fresh data.
__device__ __forceinline__ void st_bf16_wt(__hip_bfloat16* p, float v) {
    int si = (int)f2bs(v);
    asm volatile("global_store_short %0, %1, off sc0 sc1" :: "v"(p), "v"(si));
}
// CACHED 16B load (L1/L2), order-pinned asm so the 16-load window stays hoisted.
// Safe cross-XCD because: entry acquire fence invalidated stale lines; within the
// launch every hfull line is first touched only after its producers' flags.
__device__ __forceinline__ f32x4 ld16c(const void* p) {
    f32x4 r;
    asm volatile("global_load_dwordx4 %0, %1, off" : "=&v"(r) : "v"(p));
    return r;
}
__device__ __forceinline__ void vm_drain() {
    asm volatile("s_waitcnt vmcnt(0)" ::: "memory");
}

// C[M,N] = A[M,K] @ B[N,K]^T, MFMA bf16. 128x128 tile, BK=32, 4 waves (64x64 each).
// A may be tile-strided: row-tile y starts at A + y*AtileStride (elems); rows inside
// a tile are contiguous at stride K. For plain dense A pass AtileStride = 128*K.
template <typename AT, typename BT_, typename CT>
__global__ __launch_bounds__(256) void mfma_gemm_bt(const AT* __restrict__ A,
                                                    const BT_* __restrict__ B,
                                                    CT* __restrict__ C,
                                                    int M, int N, int K,
                                                    long AtileStride) {
    __shared__ __align__(16) short As[128][40];
    __shared__ __align__(16) short Bsh[128][40];
    const int tid = threadIdx.x;
    const long abase = (long)blockIdx.y * AtileStride;
    const long bm = (long)blockIdx.y * 128;
    const long bn = (long)blockIdx.x * 128;
    const int lane = tid & 63, wv = tid >> 6;
    const int l15 = lane & 15, quad = lane >> 4;
    const int wm = (wv >> 1) * 64, wn = (wv & 1) * 64;
    f32x4 acc[4][4] = {};
    for (int k0 = 0; k0 < K; k0 += 32) {
#pragma unroll
        for (int i = 0; i < 2; ++i) {
            int ch = tid + 256 * i;
            int row = ch >> 2, koff = (ch & 3) * 8;
            *(bf16x8*)&As[row][koff] = ld8(&A[abase + row * (long)K + k0 + koff]);
            *(bf16x8*)&Bsh[row][koff] = ld8(&B[(bn + row) * (long)K + k0 + koff]);
        }
        __syncthreads();
        bf16x8 af[4], bfv[4];
#pragma unroll
        for (int t = 0; t < 4; ++t) {
            af[t] = *(const bf16x8*)&As[wm + t * 16 + l15][quad * 8];
            bfv[t] = *(const bf16x8*)&Bsh[wn + t * 16 + l15][quad * 8];
        }
#pragma unroll
        for (int mt = 0; mt < 4; ++mt)
#pragma unroll
            for (int nt = 0; nt < 4; ++nt)
                acc[mt][nt] = __builtin_amdgcn_mfma_f32_16x16x32_bf16(af[mt], bfv[nt], acc[mt][nt], 0, 0, 0);
        __syncthreads();
    }
#pragma unroll
    for (int mt = 0; mt < 4; ++mt)
#pragma unroll
        for (int nt = 0; nt < 4; ++nt)
#pragma unroll
            for (int r = 0; r < 4; ++r) {
                long row = bm + wm + mt * 16 + quad * 4 + r;
                long col = bn + wn + nt * 16 + l15;
                stv(C, row * N + col, acc[mt][nt][r]);
            }
}

// Per-wave matmul slice: out[32 batch x 64 gatecols] = A[32 x K] @ Bs[64 x K]^T,
// waves split (mt, K-half). Bs rows ordered [gate g][hcol h]; acc[g] = gate g.
// 16-load bounded window (round-4/7-proven): all loads issued, vmcnt(0),
// sched_barrier, pure-register MFMA.
template <int K>
__device__ __forceinline__ void rec_mm(const __hip_bfloat16* __restrict__ Abase,
                                       const short* __restrict__ Bs, f32x4* acc,
                                       int l15, int quad, int mt, int kh) {
    constexpr int KH = K / 2;
    constexpr int NI = KH / 32;
    const __hip_bfloat16* ap = Abase + (long)(mt * 16 + l15) * K + kh * KH + quad * 8;
    const short* bp0 = Bs + l15 * BSTRIDE + kh * KH + quad * 8;
    f32x4 avr[NI];
#pragma unroll
    for (int i = 0; i < NI; ++i) avr[i] = ld16c(ap + i * 32);
    asm volatile("s_waitcnt vmcnt(0)" ::: "memory");
    __builtin_amdgcn_sched_barrier(0);
#pragma unroll
    for (int i = 0; i < NI; ++i) {
        bf16x8 av = __builtin_bit_cast(bf16x8, avr[i]);
        const short* bp = bp0 + i * 32;
        acc[0] = __builtin_amdgcn_mfma_f32_16x16x32_bf16(av, *(const bf16x8*)(bp), acc[0], 0, 0, 0);
        acc[1] = __builtin_amdgcn_mfma_f32_16x16x32_bf16(av, *(const bf16x8*)(bp + 16 * BSTRIDE), acc[1], 0, 0, 0);
        acc[2] = __builtin_amdgcn_mfma_f32_16x16x32_bf16(av, *(const bf16x8*)(bp + 32 * BSTRIDE), acc[2], 0, 0, 0);
        acc[3] = __builtin_amdgcn_mfma_f32_16x16x32_bf16(av, *(const bf16x8*)(bp + 48 * BSTRIDE), acc[3], 0, 0, 0);
    }
}

// Cooperative recurrence: 4 batch-groups x 64 WGs, XCD-aware placement:
//   x = bid%8 (XCD under round-robin dispatch), grp = x>>1, jj = (bid>>3)*2 + (x&1)
// => group g lives on XCDs {2g, 2g+1}: its h(t-1) block is fetched into at most
// 2 L2s per step; the 64-WG fan-out (16 MB/step) is served by L2, not MALL.
// Release (proven r2-r7): sc0sc1 write-through h stores -> vmcnt drain -> relaxed
// agent flag. Acquire: per-wave spin on its 32 producer flags, then CACHED A loads
// (entry fence + causality + guard pad make this safe; see ld16c comment).
__global__ __launch_bounds__(256) void lstm_rec_k(
    const __hip_bfloat16* __restrict__ h0b,   // [128][512]
    const float* __restrict__ c0,             // [128][1024]
    const float* __restrict__ Whh,            // [4096][512] fp32
    const __hip_bfloat16* __restrict__ Wcomb, // [4096][1024]
    const __hip_bfloat16* __restrict__ xg,    // [256][128][4096]
    __hip_bfloat16* __restrict__ hfull,       // [256][HSTRIDE]
    float* __restrict__ cT,                   // [128][1024]
    unsigned* __restrict__ flags) {           // [4][2][64]
    extern __shared__ char smem[];
    short* Bs = (short*)smem;                        // [64][BSTRIDE] bf16
    float* red = (float*)(smem + 64 * BSTRIDE * 2);  // [2][64][RSTRIDE] K-split partials

    // One-time invalidate of stale L1/L2 lines (previous replay's ys-GEMM cached
    // hfull lines with old values). After this, within-launch causality applies.
    __builtin_amdgcn_fence(__ATOMIC_ACQUIRE, "agent");

    const int tid = threadIdx.x;
    const int bid = blockIdx.x;
    const int x8 = bid & 7;
    const int grp = x8 >> 1;                       // 0..3, pinned to XCD pair
    const int jj = ((bid >> 3) << 1) | (x8 & 1);   // 0..63
    const int hc0 = jj * HCW;
    const int bt = grp * BT;
    const int lane = tid & 63, wv = tid >> 6;
    const int l15 = lane & 15, quad = lane >> 4;
    const int mt = wv & 1, kh = wv >> 1;
    unsigned* gflag = flags + grp * (2 * WPG);     // [2][64] for this group
    const int brow = bt + mt * 16 + quad * 4;      // + r

    // Stage B(t=0): 64 rows (g*16+h) = Whh[g*1024 + hc0 + h][0..512), fp32 -> bf16
    for (int ch = tid; ch < 64 * 64; ch += 256) {
        int row = ch >> 6, koff = (ch & 63) * 8;
        long wr = (long)(row >> 4) * HH + hc0 + (row & 15);
        *(bf16x8*)&Bs[row * BSTRIDE + koff] = ld8(&Whh[wr * PP + koff]);
    }

    float creg[2];
#pragma unroll
    for (int i = 0; i < 2; ++i) creg[i] = 0.f;
    if (kh == 0) {
        // each kh==0 wave owns rows [bt+mt*16, +16) x cols [hc0, +16): 4 c values/lane
    }
    float cregs[4];
    if (kh == 0) {
#pragma unroll
        for (int r = 0; r < 4; ++r) cregs[r] = c0[(long)(brow + r) * HH + hc0 + l15];
    }

    short xr[16];
    auto ldxg = [&](int t) {  // plain cached loads (xg read-only, runtime-flushed)
        if (kh == 0) {
            const __hip_bfloat16* xgt = xg + (long)t * BB * GG;
#pragma unroll
            for (int g = 0; g < 4; ++g)
#pragma unroll
                for (int r = 0; r < 4; ++r)
                    xr[g * 4 + r] = *(const short*)(xgt + (long)(brow + r) * GG + g * HH + hc0 + l15);
        }
    };

    // Per-wave spin: this wave's 32 producer flags (rows mt-block, cols kh-half).
    auto wave_wait = [&](int want) {
        const unsigned* fp = gflag + mt * WPG + kh * 32;
        for (;;) {
            unsigned v = __hip_atomic_load(&fp[lane & 31], __ATOMIC_RELAXED,
                                           __HIP_MEMORY_SCOPE_AGENT);
            if (__all((int)(v >= (unsigned)want))) break;
            __builtin_amdgcn_s_sleep(1);
        }
    };

    // K-split reduce + in-register cell + per-wave release (drain + own flag).
    auto finish = [&](f32x4* acc, int t, bool flag) {
        if (kh == 1) {
            float* rp = red + (mt * 64 + lane) * RSTRIDE;
#pragma unroll
            for (int g = 0; g < 4; ++g) *(f32x4*)(rp + g * 4) = acc[g];
        }
        __syncthreads();
        if (kh == 0) {
            const float* rp = red + (mt * 64 + lane) * RSTRIDE;
#pragma unroll
            for (int g = 0; g < 4; ++g) acc[g] += *(const f32x4*)(rp + g * 4);
            __hip_bfloat16* hp = hfull + (long)t * HSTRIDE;
#pragma unroll
            for (int r = 0; r < 4; ++r) {
                float gi = acc[0][r] + bs2f(xr[r]);
                float gf = acc[1][r] + bs2f(xr[4 + r]);
                float gg = acc[2][r] + bs2f(xr[8 + r]);
                float go = acc[3][r] + bs2f(xr[12 + r]);
                float i_ = 1.f / (1.f + expf(-gi));
                float f_ = 1.f / (1.f + expf(-gf));
                float g_ = tanhf(gg);
                float o_ = 1.f / (1.f + expf(-go));
                float c = f_ * cregs[r] + i_ * g_;
                cregs[r] = c;
                st_bf16_wt(hp + (long)(brow + r) * HH + hc0 + l15, o_ * tanhf(c));
            }
            vm_drain();  // this wave's 16 rows at the coherence point
            if (flag && lane == 0) {
                __hip_atomic_store(&gflag[mt * WPG + jj], (unsigned)(t + 1),
                                   __ATOMIC_RELAXED, __HIP_MEMORY_SCOPE_AGENT);
            }
        }
    };

    // ---- t = 0: A = h0b (K=512), B = Whh ----
    ldxg(0);
    __syncthreads();  // Bs staged
    {
        f32x4 acc[4] = {};
        rec_mm<PP>(h0b + (long)bt * PP, Bs, acc, l15, quad, mt, kh);
        finish(acc, 0, true);
    }
    // Restage B for t>=1: Wcomb rows (bf16, K=1024)
    for (int ch = tid; ch < 64 * 128; ch += 256) {
        int row = ch >> 7, koff = (ch & 127) * 8;
        long wr = (long)(row >> 4) * HH + hc0 + (row & 15);
        *(bf16x8*)&Bs[row * BSTRIDE + koff] = *(const bf16x8*)&Wcomb[wr * HH + koff];
    }
    __syncthreads();

    // ---- main loop ----
    for (int t = 1; t < TS; ++t) {
        ldxg(t);        // issued before the spin: latency hides under the wait
        wave_wait(t);   // per-wave: only this wave's 32 producers
        f32x4 acc[4] = {};
        rec_mm<HH>(hfull + (long)(t - 1) * HSTRIDE + (long)bt * HH, Bs, acc, l15, quad, mt, kh);
        finish(acc, t, t < TS - 1);
        // finish's internal __syncthreads orders the red-buffer WAR across waves.
    }

    if (kh == 0) {
#pragma unroll
        for (int r = 0; r < 4; ++r) cT[(long)(brow + r) * HH + hc0 + l15] = cregs[r];
    }
}

// h0 cast to bf16; Whr transpose (fp32); zero the barrier flags.
__global__ __launch_bounds__(256) void prep_k(const float* __restrict__ h0,
                                              __hip_bfloat16* __restrict__ h0b,
                                              const float* __restrict__ Whr,
                                              float* __restrict__ WhrT,
                                              unsigned* __restrict__ flags) {
    int i = blockIdx.x * 256 + threadIdx.x;
    if (i < NFLAGS) flags[i] = 0u;
    if (i < BB * PP) h0b[i] = __float2bfloat16(h0[i]);
    if (i < PP * HH) {
        int h = i / PP, p = i % PP;
        WhrT[i] = Whr[(long)p * HH + h];
    }
}

__global__ __launch_bounds__(256) void tail_k(const float* __restrict__ ys_last,
                                              float* __restrict__ hT) {
    int i = blockIdx.x * 256 + threadIdx.x;
    hT[i] = ys_last[i];
}

extern "C" void kernel_launch(void* const* d_in, const int* in_sizes, int n_in,
                              void* d_out, int out_size, void* d_ws, size_t ws_size,
                              hipStream_t stream) {
    const float* x   = (const float*)d_in[0];  // [T,B,I]
    const float* h0  = (const float*)d_in[1];  // [1,B,P]
    const float* c0  = (const float*)d_in[2];  // [1,B,H]
    const float* Wih = (const float*)d_in[3];  // [4H,I]
    const float* Whh = (const float*)d_in[4];  // [4H,P]
    const float* Whr = (const float*)d_in[5];  // [P,H]

    float* out = (float*)d_out;
    float* ys = out;                           // [T,B,P]
    float* hT = out + (long)TS * BB * PP;      // [B,P]
    float* cT = hT + (long)BB * PP;            // [B,H]

    char* ws = (char*)d_ws;
    size_t off = 0;
    __hip_bfloat16* xg = (__hip_bfloat16*)(ws + off);    off += (size_t)TS * BB * GG * 2;
    __hip_bfloat16* hfull = (__hip_bfloat16*)(ws + off); off += (size_t)TS * HSTRIDE * 2;
    __hip_bfloat16* Wcomb = (__hip_bfloat16*)(ws + off); off += (size_t)GG * HH * 2;
    float* WhrT = (float*)(ws + off);                    off += (size_t)HH * PP * 4;
    __hip_bfloat16* h0b = (__hip_bfloat16*)(ws + off);   off += (size_t)BB * PP * 2;
    unsigned* flags = (unsigned*)(ws + off);             off += 4096;

    static int smem_inited = 0;
    if (!smem_inited) {
        (void)hipFuncSetAttribute(reinterpret_cast<const void*>(lstm_rec_k),
                                  hipFuncAttributeMaxDynamicSharedMemorySize, SMEM_BYTES);
        smem_inited = 1;
    }

    dim3 blk(256);

    // prep: h0 -> bf16, Whr -> WhrT, zero flags
    prep_k<<<dim3((PP * HH) / 256), blk, 0, stream>>>(h0, h0b, Whr, WhrT, flags);

    // xg[T*B, 4H] = x @ W_ih^T   (dense A: tile stride = 128*K)
    mfma_gemm_bt<float, float, __hip_bfloat16>
        <<<dim3(GG / 128, (TS * BB) / 128), blk, 0, stream>>>(x, Wih, xg, TS * BB, GG, II, 128L * II);

    // W_comb[4H, H] = W_hh @ W_hr
    mfma_gemm_bt<float, float, __hip_bfloat16>
        <<<dim3(HH / 128, GG / 128), blk, 0, stream>>>(Whh, WhrT, Wcomb, GG, HH, PP, 128L * PP);

    // full recurrence (cooperative launch for co-residency; per-wave flag protocol)
    {
        const __hip_bfloat16* a0 = h0b;
        const float* a1 = c0;
        const float* a2 = Whh;
        const __hip_bfloat16* a3 = Wcomb;
        const __hip_bfloat16* a4 = xg;
        __hip_bfloat16* a5 = hfull;
        float* a6 = cT;
        unsigned* a7 = flags;
        void* args[] = {(void*)&a0, (void*)&a1, (void*)&a2, (void*)&a3,
                        (void*)&a4, (void*)&a5, (void*)&a6, (void*)&a7};
        (void)hipLaunchCooperativeKernel(reinterpret_cast<void*>(lstm_rec_k),
                                         dim3(NWG), blk, args, SMEM_BYTES, stream);
    }

    // ys[T*B, P] = hfull @ W_hr^T   (strided A: one 128-row tile = one timestep)
    mfma_gemm_bt<__hip_bfloat16, float, float>
        <<<dim3(PP / 128, (TS * BB) / 128), blk, 0, stream>>>(hfull, Whr, ys, TS * BB, PP, HH, (long)HSTRIDE);

    // hT = ys[T-1]
    tail_k<<<dim3((BB * PP) / 256), blk, 0, stream>>>(ys + (long)(TS - 1) * BB * PP, hT);
}

// Round 11
// 2750.094 us; speedup vs baseline: 1.2439x; 1.2206x over previous
//
#include <hip/hip_runtime.h>
#include <hip/hip_bf16.h>

#define TS 256
#define BB 128
#define II 1024
#define HH 1024
#define PP 512
#define GG 4096  // 4*H
#define NWG 256
#define NGRP 4
#define WPG 64        // WGs per group (hidden tiles)
#define BT 32         // batch rows per group
#define HCW 16        // hidden cols per WG
#define BSTRIDE 1032  // shorts per Bs row (pad 1024+8 to spread banks)
#define RSTRIDE 20    // floats per red row (pad 16+4)
#define NFLAGS (NGRP * 2 * WPG)
#define SMEM_BYTES (64 * BSTRIDE * 2 + 2 * 64 * RSTRIDE * 4)  // 142336

typedef __attribute__((ext_vector_type(8))) short bf16x8;
typedef __attribute__((ext_vector_type(4))) float f32x4;

__device__ __forceinline__ short f2bs(float f) {
    __hip_bfloat16 h = __float2bfloat16(f);
    return __builtin_bit_cast(short, h);
}
__device__ __forceinline__ float bs2f(short s) {
    return __bfloat162float(__builtin_bit_cast(__hip_bfloat16, s));
}

__device__ __forceinline__ bf16x8 ld8(const __hip_bfloat16* p) {
    return *(const bf16x8*)p;
}
__device__ __forceinline__ bf16x8 ld8(const float* p) {
    f32x4 lo = *(const f32x4*)p;
    f32x4 hi = *(const f32x4*)(p + 4);
    bf16x8 r;
#pragma unroll
    for (int i = 0; i < 4; ++i) { r[i] = f2bs(lo[i]); r[4 + i] = f2bs(hi[i]); }
    return r;
}

__device__ __forceinline__ void stv(float* p, long i, float v) { p[i] = v; }
__device__ __forceinline__ void stv(__hip_bfloat16* p, long i, float v) { p[i] = __float2bfloat16(v); }

// Write-through bf16 store (round-4 proven): lands at the device coherence point.
__device__ __forceinline__ void st_bf16_wt(__hip_bfloat16* p, float v) {
    int si = (int)f2bs(v);
    asm volatile("global_store_short %0, %1, off sc1" :: "v"(p), "v"(si));
}
// Coherence-point 16B load (round-4 proven). asm volatile => program-order pinned.
__device__ __forceinline__ f32x4 ld16_mall(const void* p) {
    f32x4 r;
    asm volatile("global_load_dwordx4 %0, %1, off sc1" : "=&v"(r) : "v"(p));
    return r;
}
__device__ __forceinline__ void vm_drain() {
    asm volatile("s_waitcnt vmcnt(0)" ::: "memory");
}

// Async global->LDS, 16B per lane. LDS dest = wave-uniform base + lane*16.
__device__ __forceinline__ void gload_lds16(const void* g, void* l) {
    __builtin_amdgcn_global_load_lds(
        (const __attribute__((address_space(1))) void*)g,
        (__attribute__((address_space(3))) void*)l, 16, 0, 0);
}

// ---- slow GEMM (fp32 inputs; kept only for the tiny Wcomb product) ----
template <typename AT, typename BT_, typename CT>
__global__ __launch_bounds__(256) void mfma_gemm_bt(const AT* __restrict__ A,
                                                    const BT_* __restrict__ B,
                                                    CT* __restrict__ C,
                                                    int M, int N, int K) {
    __shared__ __align__(16) short As[128][40];
    __shared__ __align__(16) short Bsh[128][40];
    const int tid = threadIdx.x;
    const long bm = (long)blockIdx.y * 128;
    const long bn = (long)blockIdx.x * 128;
    const int lane = tid & 63, wv = tid >> 6;
    const int l15 = lane & 15, quad = lane >> 4;
    const int wm = (wv >> 1) * 64, wn = (wv & 1) * 64;
    f32x4 acc[4][4] = {};
    for (int k0 = 0; k0 < K; k0 += 32) {
#pragma unroll
        for (int i = 0; i < 2; ++i) {
            int ch = tid + 256 * i;
            int row = ch >> 2, koff = (ch & 3) * 8;
            *(bf16x8*)&As[row][koff] = ld8(&A[(bm + row) * (long)K + k0 + koff]);
            *(bf16x8*)&Bsh[row][koff] = ld8(&B[(bn + row) * (long)K + k0 + koff]);
        }
        __syncthreads();
        bf16x8 af[4], bfv[4];
#pragma unroll
        for (int t = 0; t < 4; ++t) {
            af[t] = *(const bf16x8*)&As[wm + t * 16 + l15][quad * 8];
            bfv[t] = *(const bf16x8*)&Bsh[wn + t * 16 + l15][quad * 8];
        }
#pragma unroll
        for (int mt = 0; mt < 4; ++mt)
#pragma unroll
            for (int nt = 0; nt < 4; ++nt)
                acc[mt][nt] = __builtin_amdgcn_mfma_f32_16x16x32_bf16(af[mt], bfv[nt], acc[mt][nt], 0, 0, 0);
        __syncthreads();
    }
#pragma unroll
    for (int mt = 0; mt < 4; ++mt)
#pragma unroll
        for (int nt = 0; nt < 4; ++nt)
#pragma unroll
            for (int r = 0; r < 4; ++r) {
                long row = bm + wm + mt * 16 + quad * 4 + r;
                long col = bn + wn + nt * 16 + l15;
                stv(C, row * N + col, acc[mt][nt][r]);
            }
}

// ---- fast GEMM: bf16 A/B, global_load_lds staging (m97 structure) ----
// C[M,N] = A[M,K] @ B[N,K]^T. 128x128 tile, BK=32, 4 waves.
// Staging: tile = 128x32 bf16 = 8 chunks x 1024 B; chunk c rows [16c,+16);
// wave wv issues chunks {wv, wv+4}; lane l -> LDS shorts [c*512 + l*8, +8)
// == row 16c + l/4, k = (l%4)*8 (linear dest base + lane*16B).
template <typename CT>
__global__ __launch_bounds__(256) void gemm_bt_fast(const __hip_bfloat16* __restrict__ A,
                                                    const __hip_bfloat16* __restrict__ B,
                                                    CT* __restrict__ C,
                                                    int M, int N, int K) {
    __shared__ __align__(16) short As[128 * 32];
    __shared__ __align__(16) short Bs[128 * 32];
    const int tid = threadIdx.x;
    const int lane = tid & 63, wv = tid >> 6;
    const int l15 = lane & 15, quad = lane >> 4;
    const long bm = (long)blockIdx.y * 128;
    const long bn = (long)blockIdx.x * 128;
    const int wm = (wv >> 1) * 64, wn = (wv & 1) * 64;
    const int srow = lane >> 2;        // 0..15 within chunk
    const int skof = (lane & 3) * 8;   // k offset 0,8,16,24
    const int c1 = wv, c2 = wv + 4;    // this wave's chunks
    f32x4 acc[4][4] = {};
    for (int k0 = 0; k0 < K; k0 += 32) {
        gload_lds16(A + (bm + c1 * 16 + srow) * (long)K + k0 + skof, As + c1 * 512);
        gload_lds16(B + (bn + c1 * 16 + srow) * (long)K + k0 + skof, Bs + c1 * 512);
        gload_lds16(A + (bm + c2 * 16 + srow) * (long)K + k0 + skof, As + c2 * 512);
        gload_lds16(B + (bn + c2 * 16 + srow) * (long)K + k0 + skof, Bs + c2 * 512);
        __syncthreads();  // compiler drains vmcnt before s_barrier
        bf16x8 af[4], bfv[4];
#pragma unroll
        for (int t = 0; t < 4; ++t) {
            af[t] = *(const bf16x8*)&As[(wm + t * 16 + l15) * 32 + quad * 8];
            bfv[t] = *(const bf16x8*)&Bs[(wn + t * 16 + l15) * 32 + quad * 8];
        }
#pragma unroll
        for (int mt = 0; mt < 4; ++mt)
#pragma unroll
            for (int nt = 0; nt < 4; ++nt)
                acc[mt][nt] = __builtin_amdgcn_mfma_f32_16x16x32_bf16(af[mt], bfv[nt], acc[mt][nt], 0, 0, 0);
        __syncthreads();
    }
#pragma unroll
    for (int mt = 0; mt < 4; ++mt)
#pragma unroll
        for (int nt = 0; nt < 4; ++nt)
#pragma unroll
            for (int r = 0; r < 4; ++r) {
                long row = bm + wm + mt * 16 + quad * 4 + r;
                long col = bn + wn + nt * 16 + l15;
                stv(C, row * N + col, acc[mt][nt][r]);
            }
}

// fp32 -> bf16 bulk convert (n % 8 == 0), vectorized.
__global__ __launch_bounds__(256) void cvt_bf16_k(const float* __restrict__ in,
                                                  __hip_bfloat16* __restrict__ out,
                                                  long n) {
    long i = ((long)blockIdx.x * 256 + threadIdx.x) * 8;
    if (i < n) {
        f32x4 lo = *(const f32x4*)(in + i);
        f32x4 hi = *(const f32x4*)(in + i + 4);
        bf16x8 r;
#pragma unroll
        for (int j = 0; j < 4; ++j) { r[j] = f2bs(lo[j]); r[4 + j] = f2bs(hi[j]); }
        *(bf16x8*)(out + i) = r;
    }
}

// ---- recurrence kernel: byte-for-byte the round-4 (2047 us) version ----
template <int K>
__device__ __forceinline__ void rec_mm(const __hip_bfloat16* __restrict__ Abase,
                                       const short* __restrict__ Bs, f32x4* acc,
                                       int l15, int quad, int mt, int kh) {
    constexpr int KH = K / 2;
    constexpr int NI = KH / 32;
    const __hip_bfloat16* ap = Abase + (long)(mt * 16 + l15) * K + kh * KH + quad * 8;
    const short* bp0 = Bs + l15 * BSTRIDE + kh * KH + quad * 8;
    f32x4 avr[NI];
#pragma unroll
    for (int i = 0; i < NI; ++i) avr[i] = ld16_mall(ap + i * 32);
    asm volatile("s_waitcnt vmcnt(0)" ::: "memory");
    __builtin_amdgcn_sched_barrier(0);
#pragma unroll
    for (int i = 0; i < NI; ++i) {
        bf16x8 av = __builtin_bit_cast(bf16x8, avr[i]);
        const short* bp = bp0 + i * 32;
        acc[0] = __builtin_amdgcn_mfma_f32_16x16x32_bf16(av, *(const bf16x8*)(bp), acc[0], 0, 0, 0);
        acc[1] = __builtin_amdgcn_mfma_f32_16x16x32_bf16(av, *(const bf16x8*)(bp + 16 * BSTRIDE), acc[1], 0, 0, 0);
        acc[2] = __builtin_amdgcn_mfma_f32_16x16x32_bf16(av, *(const bf16x8*)(bp + 32 * BSTRIDE), acc[2], 0, 0, 0);
        acc[3] = __builtin_amdgcn_mfma_f32_16x16x32_bf16(av, *(const bf16x8*)(bp + 48 * BSTRIDE), acc[3], 0, 0, 0);
    }
}

__global__ __launch_bounds__(256) void lstm_rec_k(
    const __hip_bfloat16* __restrict__ h0b,   // [128][512]
    const float* __restrict__ c0,             // [128][1024]
    const float* __restrict__ Whh,            // [4096][512] fp32
    const __hip_bfloat16* __restrict__ Wcomb, // [4096][1024]
    const __hip_bfloat16* __restrict__ xg,    // [256][128][4096]
    __hip_bfloat16* __restrict__ hfull,       // [256][128][1024]
    float* __restrict__ cT,                   // [128][1024]
    unsigned* __restrict__ flags) {           // [4][2][64]
    extern __shared__ char smem[];
    short* Bs = (short*)smem;                        // [64][BSTRIDE] bf16
    float* red = (float*)(smem + 64 * BSTRIDE * 2);  // [2][64][RSTRIDE] K-split partials

    const int tid = threadIdx.x;
    const int wg = blockIdx.x;
    const int grp = wg >> 6;
    const int jj = wg & 63;
    const int hc0 = jj * HCW;
    const int bt = grp * BT;
    const int lane = tid & 63, wv = tid >> 6;
    const int l15 = lane & 15, quad = lane >> 4;
    const int mt = wv & 1, kh = wv >> 1;
    unsigned* gflag = flags + grp * (2 * WPG);
    const int brow = bt + mt * 16 + quad * 4;

    for (int ch = tid; ch < 64 * 64; ch += 256) {
        int row = ch >> 6, koff = (ch & 63) * 8;
        long wr = (long)(row >> 4) * HH + hc0 + (row & 15);
        *(bf16x8*)&Bs[row * BSTRIDE + koff] = ld8(&Whh[wr * PP + koff]);
    }

    float cregs[4];
    if (kh == 0) {
#pragma unroll
        for (int r = 0; r < 4; ++r) cregs[r] = c0[(long)(brow + r) * HH + hc0 + l15];
    }

    short xr[16];
    auto ldxg = [&](int t) {
        if (kh == 0) {
            const __hip_bfloat16* xgt = xg + (long)t * BB * GG;
#pragma unroll
            for (int g = 0; g < 4; ++g)
#pragma unroll
                for (int r = 0; r < 4; ++r)
                    xr[g * 4 + r] = *(const short*)(xgt + (long)(brow + r) * GG + g * HH + hc0 + l15);
        }
    };

    auto wave_wait = [&](int want) {
        const unsigned* fp = gflag + mt * WPG + kh * 32;
        for (;;) {
            unsigned v = __hip_atomic_load(&fp[lane & 31], __ATOMIC_RELAXED,
                                           __HIP_MEMORY_SCOPE_AGENT);
            if (__all((int)(v >= (unsigned)want))) break;
            __builtin_amdgcn_s_sleep(1);
        }
    };

    auto finish = [&](f32x4* acc, int t, bool flag) {
        if (kh == 1) {
            float* rp = red + (mt * 64 + lane) * RSTRIDE;
#pragma unroll
            for (int g = 0; g < 4; ++g) *(f32x4*)(rp + g * 4) = acc[g];
        }
        __syncthreads();
        if (kh == 0) {
            const float* rp = red + (mt * 64 + lane) * RSTRIDE;
#pragma unroll
            for (int g = 0; g < 4; ++g) acc[g] += *(const f32x4*)(rp + g * 4);
            __hip_bfloat16* hp = hfull + (long)t * BB * HH;
#pragma unroll
            for (int r = 0; r < 4; ++r) {
                float gi = acc[0][r] + bs2f(xr[r]);
                float gf = acc[1][r] + bs2f(xr[4 + r]);
                float gg = acc[2][r] + bs2f(xr[8 + r]);
                float go = acc[3][r] + bs2f(xr[12 + r]);
                float i_ = 1.f / (1.f + expf(-gi));
                float f_ = 1.f / (1.f + expf(-gf));
                float g_ = tanhf(gg);
                float o_ = 1.f / (1.f + expf(-go));
                float c = f_ * cregs[r] + i_ * g_;
                cregs[r] = c;
                st_bf16_wt(hp + (long)(brow + r) * HH + hc0 + l15, o_ * tanhf(c));
            }
            vm_drain();
            if (flag && lane == 0) {
                __hip_atomic_store(&gflag[mt * WPG + jj], (unsigned)(t + 1),
                                   __ATOMIC_RELAXED, __HIP_MEMORY_SCOPE_AGENT);
            }
        }
    };

    // ---- t = 0: A = h0b (K=512), B = Whh ----
    ldxg(0);
    __syncthreads();
    {
        f32x4 acc[4] = {};
        rec_mm<PP>(h0b + (long)bt * PP, Bs, acc, l15, quad, mt, kh);
        finish(acc, 0, true);
    }
    // Restage B for t>=1 (Bs reads of t=0 completed before finish's barrier).
    for (int ch = tid; ch < 64 * 128; ch += 256) {
        int row = ch >> 7, koff = (ch & 127) * 8;
        long wr = (long)(row >> 4) * HH + hc0 + (row & 15);
        *(bf16x8*)&Bs[row * BSTRIDE + koff] = *(const bf16x8*)&Wcomb[wr * HH + koff];
    }
    __syncthreads();

    for (int t = 1; t < TS; ++t) {
        ldxg(t);
        wave_wait(t);
        f32x4 acc[4] = {};
        rec_mm<HH>(hfull + ((long)(t - 1) * BB + bt) * HH, Bs, acc, l15, quad, mt, kh);
        finish(acc, t, t < TS - 1);
    }

    if (kh == 0) {
#pragma unroll
        for (int r = 0; r < 4; ++r) cT[(long)(brow + r) * HH + hc0 + l15] = cregs[r];
    }
}

// h0 -> bf16; Whr transpose (fp32, for Wcomb GEMM only); zero flags.
__global__ __launch_bounds__(256) void prep_k(const float* __restrict__ h0,
                                              __hip_bfloat16* __restrict__ h0b,
                                              const float* __restrict__ Whr,
                                              float* __restrict__ WhrT,
                                              unsigned* __restrict__ flags) {
    int i = blockIdx.x * 256 + threadIdx.x;
    if (i < NFLAGS) flags[i] = 0u;
    if (i < BB * PP) h0b[i] = __float2bfloat16(h0[i]);
    if (i < PP * HH) {
        int h = i / PP, p = i % PP;
        WhrT[i] = Whr[(long)p * HH + h];
    }
}

__global__ __launch_bounds__(256) void tail_k(const float* __restrict__ ys_last,
                                              float* __restrict__ hT) {
    int i = blockIdx.x * 256 + threadIdx.x;
    hT[i] = ys_last[i];
}

extern "C" void kernel_launch(void* const* d_in, const int* in_sizes, int n_in,
                              void* d_out, int out_size, void* d_ws, size_t ws_size,
                              hipStream_t stream) {
    const float* x   = (const float*)d_in[0];  // [T,B,I]
    const float* h0  = (const float*)d_in[1];  // [1,B,P]
    const float* c0  = (const float*)d_in[2];  // [1,B,H]
    const float* Wih = (const float*)d_in[3];  // [4H,I]
    const float* Whh = (const float*)d_in[4];  // [4H,P]
    const float* Whr = (const float*)d_in[5];  // [P,H]

    float* out = (float*)d_out;
    float* ys = out;                           // [T,B,P]
    float* hT = out + (long)TS * BB * PP;      // [B,P]
    float* cT = hT + (long)BB * PP;            // [B,H]

    char* ws = (char*)d_ws;
    size_t off = 0;
    __hip_bfloat16* xg = (__hip_bfloat16*)(ws + off);    off += (size_t)TS * BB * GG * 2;
    __hip_bfloat16* hfull = (__hip_bfloat16*)(ws + off); off += (size_t)TS * BB * HH * 2;
    __hip_bfloat16* Wcomb = (__hip_bfloat16*)(ws + off); off += (size_t)GG * HH * 2;
    float* WhrT = (float*)(ws + off);                    off += (size_t)HH * PP * 4;
    __hip_bfloat16* Whrb = (__hip_bfloat16*)(ws + off);  off += (size_t)PP * HH * 2;
    __hip_bfloat16* h0b = (__hip_bfloat16*)(ws + off);   off += (size_t)BB * PP * 2;
    unsigned* flags = (unsigned*)(ws + off);             off += 4096;

    // Aliases (lifetimes disjoint, same stream => ordered):
    //   xb lives in hfull's slot (hfull written only by the later rec kernel)
    //   Wib lives in Wcomb's slot (Wcomb written only after the xg GEMM)
    __hip_bfloat16* xb = hfull;    // [T*B][I] bf16
    __hip_bfloat16* Wib = Wcomb;   // [4H][I] bf16

    (void)hipFuncSetAttribute(reinterpret_cast<const void*>(lstm_rec_k),
                              hipFuncAttributeMaxDynamicSharedMemorySize, SMEM_BYTES);

    dim3 blk(256);

    // prep: h0 -> bf16, Whr -> WhrT (fp32), zero flags
    prep_k<<<dim3((PP * HH) / 256), blk, 0, stream>>>(h0, h0b, Whr, WhrT, flags);

    // bf16 conversions for the fast GEMM path
    cvt_bf16_k<<<dim3((TS * BB * II) / 8 / 256), blk, 0, stream>>>(x, xb, (long)TS * BB * II);
    cvt_bf16_k<<<dim3((GG * II) / 8 / 256), blk, 0, stream>>>(Wih, Wib, (long)GG * II);
    // Whrb: UNtransposed bf16 copy of Whr [P][H] — the ys GEMM's B operand (N=P, K=H).
    cvt_bf16_k<<<dim3((PP * HH) / 8 / 256), blk, 0, stream>>>(Whr, Whrb, (long)PP * HH);

    // xg[T*B, 4H] = xb @ Wib^T   (fast path: global_load_lds staging)
    gemm_bt_fast<__hip_bfloat16>
        <<<dim3(GG / 128, (TS * BB) / 128), blk, 0, stream>>>(xb, Wib, xg, TS * BB, GG, II);

    // W_comb[4H, H] = W_hh @ W_hr  (tiny; old fp32 path; overwrites Wib slot)
    mfma_gemm_bt<float, float, __hip_bfloat16>
        <<<dim3(HH / 128, GG / 128), blk, 0, stream>>>(Whh, WhrT, Wcomb, GG, HH, PP);

    // full recurrence (round-4 proven kernel; overwrites xb slot with hfull)
    {
        const __hip_bfloat16* a0 = h0b;
        const float* a1 = c0;
        const float* a2 = Whh;
        const __hip_bfloat16* a3 = Wcomb;
        const __hip_bfloat16* a4 = xg;
        __hip_bfloat16* a5 = hfull;
        float* a6 = cT;
        unsigned* a7 = flags;
        void* args[] = {(void*)&a0, (void*)&a1, (void*)&a2, (void*)&a3,
                        (void*)&a4, (void*)&a5, (void*)&a6, (void*)&a7};
        (void)hipLaunchCooperativeKernel(reinterpret_cast<void*>(lstm_rec_k),
                                         dim3(NWG), blk, args, SMEM_BYTES, stream);
    }

    // ys[T*B, P] = hfull @ Whrb^T  (fast path; B = Whr [P][H] in bf16)
    gemm_bt_fast<float>
        <<<dim3(PP / 128, (TS * BB) / 128), blk, 0, stream>>>(hfull, Whrb, ys, TS * BB, PP, HH);

    // hT = ys[T-1]
    tail_k<<<dim3((BB * PP) / 256), blk, 0, stream>>>(ys + (long)(TS - 1) * BB * PP, hT);
}